// Round 4
// baseline (29090.778 us; speedup 1.0000x reference)
//
#include <hip/hip_runtime.h>
#include <hip/hip_bf16.h>
#include <cstdint>

#define Hh   1024
#define G3   3072
#define POISON_U 0xFFFFFFFFu

__device__ __forceinline__ float sigmoidf_(float x) { return 1.f / (1.f + __expf(-x)); }

__device__ __forceinline__ float ld_agent(const float* p) {
    return __hip_atomic_load(p, __ATOMIC_RELAXED, __HIP_MEMORY_SCOPE_AGENT);
}
__device__ __forceinline__ void st_agent(float* p, float v) {
    __hip_atomic_store(p, v, __ATOMIC_RELAXED, __HIP_MEMORY_SCOPE_AGENT);
}
__device__ __forceinline__ bool okf(float v) { return __float_as_uint(v) != POISON_U; }

// ---------------- gather: x_enc = emb[char_seq], x_dec = emb[[sos]+target[:-1]] ----------------
__global__ __launch_bounds__(128) void gather_emb(const int* __restrict__ char_seq,
    const int* __restrict__ target, const int* __restrict__ sos,
    const float* __restrict__ emb, float* __restrict__ x_enc, float* __restrict__ x_dec)
{
    const int r = blockIdx.x;
    int id; float* dst;
    if (r < 1024) { id = char_seq[r]; dst = x_enc + (size_t)r * 512; }
    else {
        const int rd = r - 1024;
        id = (rd == 0) ? sos[0] : target[rd - 1];
        dst = x_dec + (size_t)rd * 512;
    }
    const float4* src = (const float4*)(emb + (size_t)id * 512);
    ((float4*)dst)[threadIdx.x] = src[threadIdx.x];
}

// ---------------- GEMM: C[M x N] = A[M x K] @ W[N x K]^T + bias[N]  (f32, 64x64 tile) ----------------
__global__ __launch_bounds__(256) void gemm_nt(const float* __restrict__ A,
    const float* __restrict__ W, const float* __restrict__ bias,
    float* __restrict__ C, int M, int N, int K)
{
    __shared__ float As[16][68];
    __shared__ float Ws[16][68];
    const int tid = threadIdx.x;
    const int tx = tid & 15, ty = tid >> 4;
    const int row0 = blockIdx.y * 64, col0 = blockIdx.x * 64;
    const int lr = tid >> 2;          // 0..63
    const int ls = (tid & 3) << 2;    // 0,4,8,12
    float acc[4][4] = {};
    for (int k0 = 0; k0 < K; k0 += 16) {
        const float4 a4 = *(const float4*)(A + (size_t)(row0 + lr) * K + k0 + ls);
        const float4 w4 = *(const float4*)(W + (size_t)(col0 + lr) * K + k0 + ls);
        As[ls + 0][lr] = a4.x; As[ls + 1][lr] = a4.y; As[ls + 2][lr] = a4.z; As[ls + 3][lr] = a4.w;
        Ws[ls + 0][lr] = w4.x; Ws[ls + 1][lr] = w4.y; Ws[ls + 2][lr] = w4.z; Ws[ls + 3][lr] = w4.w;
        __syncthreads();
        #pragma unroll
        for (int k = 0; k < 16; ++k) {
            const float4 a = *(const float4*)&As[k][ty << 2];
            const float4 w = *(const float4*)&Ws[k][tx << 2];
            const float av[4] = {a.x, a.y, a.z, a.w};
            const float wv[4] = {w.x, w.y, w.z, w.w};
            #pragma unroll
            for (int i = 0; i < 4; ++i)
                #pragma unroll
                for (int j = 0; j < 4; ++j)
                    acc[i][j] += av[i] * wv[j];
        }
        __syncthreads();
    }
    const int cc = col0 + (tx << 2);
    #pragma unroll
    for (int i = 0; i < 4; ++i) {
        float4 o;
        o.x = acc[i][0] + bias[cc + 0];
        o.y = acc[i][1] + bias[cc + 1];
        o.z = acc[i][2] + bias[cc + 2];
        o.w = acc[i][3] + bias[cc + 3];
        *(float4*)(C + (size_t)(row0 + (ty << 2) + i) * N + cc) = o;
    }
}

// ---------------- fused 2-layer GRU: register weights, registers-only poison-poll exchange ----------------
// Grid: 256 WGs x 512 threads = 2048 waves; wave = one hidden unit of one layer.
// WGs 0..127 = layer0 units, 128..255 = layer1 units. No LDS, no barriers in the loop:
// lane ln polls its 16 h-elements (4*ln+q + 256*j) + one uniform h_prev[uu] directly to VGPRs.
// hs rows poisoned 0xFFFFFFFF at launch; writers publish via relaxed agent 4B stores.
// L0 at t: consumes row t -> produces row t+1. L1 at t: consumes hs0[t+1] + hs1[t] -> hs1[t+1].
__global__ __launch_bounds__(512) void fused_gru2(
    const float* __restrict__ gx0,
    const float* __restrict__ whh0, const float* __restrict__ bhh0,
    const float* __restrict__ wih1, const float* __restrict__ bih1,
    const float* __restrict__ whh1, const float* __restrict__ bhh1,
    const float* __restrict__ h0i, const float* __restrict__ h1i,
    float* __restrict__ hs0, float* __restrict__ hs1, int S)
{
    const int tid = threadIdx.x;
    const int wg  = blockIdx.x;
    const bool isL1 = (wg >= 128);
    const int ln = tid & 63;
    const int wv = tid >> 6;                             // 0..7
    const int uu = ((isL1 ? wg - 128 : wg) << 3) + wv;   // hidden unit 0..1023
    const int base = ln << 2;                            // element offset of this lane's slice

    if (!isL1) {
        // ---- layer 0: weights = whh0 rows for unit uu ----
        float4 wa[3][4];
        #pragma unroll
        for (int g = 0; g < 3; ++g)
            #pragma unroll
            for (int j = 0; j < 4; ++j)
                wa[g][j] = *(const float4*)(whh0 + (size_t)(g * Hh + uu) * Hh + base + (j << 8));
        const float ba_r = bhh0[uu], ba_z = bhh0[Hh + uu], ba_n = bhh0[2 * Hh + uu];

        for (int t = 0; t < S; ++t) {
            const float* gxt = gx0 + (size_t)t * G3 + uu;
            const float xr = gxt[0], xz = gxt[Hh], xn = gxt[2 * Hh];
            const float* row = t ? (hs0 + (size_t)t * Hh) : h0i;
            float4 h4[4]; float hp;
            int guard = 0; bool ok;
            do {
                #pragma unroll
                for (int j = 0; j < 4; ++j) {
                    const float* p = row + base + (j << 8);
                    h4[j].x = ld_agent(p + 0); h4[j].y = ld_agent(p + 1);
                    h4[j].z = ld_agent(p + 2); h4[j].w = ld_agent(p + 3);
                }
                hp = ld_agent(row + uu);
                ok = okf(hp);
                #pragma unroll
                for (int j = 0; j < 4; ++j)
                    ok = ok && okf(h4[j].x) && okf(h4[j].y) && okf(h4[j].z) && okf(h4[j].w);
                if (!ok) __builtin_amdgcn_s_sleep(1);
            } while (!ok && ++guard < (1 << 20));

            float ar = 0.f, az = 0.f, an = 0.f;
            #pragma unroll
            for (int j = 0; j < 4; ++j) {
                ar += h4[j].x * wa[0][j].x + h4[j].y * wa[0][j].y + h4[j].z * wa[0][j].z + h4[j].w * wa[0][j].w;
                az += h4[j].x * wa[1][j].x + h4[j].y * wa[1][j].y + h4[j].z * wa[1][j].z + h4[j].w * wa[1][j].w;
                an += h4[j].x * wa[2][j].x + h4[j].y * wa[2][j].y + h4[j].z * wa[2][j].z + h4[j].w * wa[2][j].w;
            }
            #pragma unroll
            for (int m = 1; m < 64; m <<= 1) {
                ar += __shfl_xor(ar, m); az += __shfl_xor(az, m); an += __shfl_xor(an, m);
            }
            const float rr = sigmoidf_(xr + ar + ba_r);
            const float zz = sigmoidf_(xz + az + ba_z);
            const float nn = tanhf(xn + rr * (an + ba_n));
            const float hnew = (1.f - zz) * nn + zz * hp;
            if (ln == 0) st_agent(hs0 + (size_t)(t + 1) * Hh + uu, hnew);
        }
    } else {
        // ---- layer 1: weights = wih1 rows (input = h0) + whh1 rows ----
        float4 wa[3][4], wb[3][4];
        #pragma unroll
        for (int g = 0; g < 3; ++g)
            #pragma unroll
            for (int j = 0; j < 4; ++j) {
                wa[g][j] = *(const float4*)(wih1 + (size_t)(g * Hh + uu) * Hh + base + (j << 8));
                wb[g][j] = *(const float4*)(whh1 + (size_t)(g * Hh + uu) * Hh + base + (j << 8));
            }
        const float ba_r = bih1[uu], ba_z = bih1[Hh + uu], ba_n = bih1[2 * Hh + uu];
        const float bb_r = bhh1[uu], bb_z = bhh1[Hh + uu], bb_n = bhh1[2 * Hh + uu];

        for (int t = 0; t < S; ++t) {
            const float* rx = hs0 + (size_t)(t + 1) * Hh;          // always in-flight
            const float* rh = t ? (hs1 + (size_t)t * Hh) : h1i;
            float4 x4[4], h4[4]; float hp;
            int guard = 0; bool ok;
            do {
                #pragma unroll
                for (int j = 0; j < 4; ++j) {
                    const float* px = rx + base + (j << 8);
                    const float* ph = rh + base + (j << 8);
                    x4[j].x = ld_agent(px + 0); x4[j].y = ld_agent(px + 1);
                    x4[j].z = ld_agent(px + 2); x4[j].w = ld_agent(px + 3);
                    h4[j].x = ld_agent(ph + 0); h4[j].y = ld_agent(ph + 1);
                    h4[j].z = ld_agent(ph + 2); h4[j].w = ld_agent(ph + 3);
                }
                hp = ld_agent(rh + uu);
                ok = okf(hp);
                #pragma unroll
                for (int j = 0; j < 4; ++j)
                    ok = ok && okf(x4[j].x) && okf(x4[j].y) && okf(x4[j].z) && okf(x4[j].w)
                            && okf(h4[j].x) && okf(h4[j].y) && okf(h4[j].z) && okf(h4[j].w);
                if (!ok) __builtin_amdgcn_s_sleep(1);
            } while (!ok && ++guard < (1 << 20));

            float ar = 0.f, az = 0.f, an = 0.f, hr = 0.f, hz = 0.f, hn = 0.f;
            #pragma unroll
            for (int j = 0; j < 4; ++j) {
                ar += x4[j].x * wa[0][j].x + x4[j].y * wa[0][j].y + x4[j].z * wa[0][j].z + x4[j].w * wa[0][j].w;
                az += x4[j].x * wa[1][j].x + x4[j].y * wa[1][j].y + x4[j].z * wa[1][j].z + x4[j].w * wa[1][j].w;
                an += x4[j].x * wa[2][j].x + x4[j].y * wa[2][j].y + x4[j].z * wa[2][j].z + x4[j].w * wa[2][j].w;
                hr += h4[j].x * wb[0][j].x + h4[j].y * wb[0][j].y + h4[j].z * wb[0][j].z + h4[j].w * wb[0][j].w;
                hz += h4[j].x * wb[1][j].x + h4[j].y * wb[1][j].y + h4[j].z * wb[1][j].z + h4[j].w * wb[1][j].w;
                hn += h4[j].x * wb[2][j].x + h4[j].y * wb[2][j].y + h4[j].z * wb[2][j].z + h4[j].w * wb[2][j].w;
            }
            #pragma unroll
            for (int m = 1; m < 64; m <<= 1) {
                ar += __shfl_xor(ar, m); az += __shfl_xor(az, m); an += __shfl_xor(an, m);
                hr += __shfl_xor(hr, m); hz += __shfl_xor(hz, m); hn += __shfl_xor(hn, m);
            }
            const float rr = sigmoidf_((ar + ba_r) + (hr + bb_r));
            const float zz = sigmoidf_((az + ba_z) + (hz + bb_z));
            const float nn = tanhf((an + ba_n) + rr * (hn + bb_n));
            const float hnew = (1.f - zz) * nn + zz * hp;
            if (ln == 0) st_agent(hs1 + (size_t)(t + 1) * Hh + uu, hnew);
        }
    }
}

// ---------------- char_states_out: out[t][0:1024]=hs_d0[t+1], out[t][1024:2048]=hs_d1[t+1] ----------------
__global__ __launch_bounds__(256) void copy_states(const float* __restrict__ hs0,
    const float* __restrict__ hs1, float* __restrict__ out)
{
    const int f = blockIdx.x * 256 + threadIdx.x;  // float4 index, total 262144
    const int t = f >> 9;
    const int c = f & 511;
    const float* src = (c < 256) ? (hs0 + (((size_t)t + 1) << 10) + (c << 2))
                                 : (hs1 + (((size_t)t + 1) << 10) + ((c - 256) << 2));
    *(float4*)(out + ((size_t)f << 2)) = *(const float4*)src;
}

// ---------------- label heads on char_scores[last] + zero padding ----------------
__global__ __launch_bounds__(256) void labels_kernel(const float* __restrict__ scores,
    const float* __restrict__ w0, const float* __restrict__ b0,
    const float* __restrict__ w1, const float* __restrict__ b1,
    const float* __restrict__ w2, const float* __restrict__ b2,
    float* __restrict__ out)
{
    __shared__ float sl[Hh];
    const int tid = threadIdx.x;
    for (int i = tid; i < Hh; i += 256) sl[i] = scores[(size_t)511 * Hh + i];
    for (int i = tid; i < 240; i += 256) out[i] = 0.f;
    __syncthreads();
    const int wv = tid >> 6, ln = tid & 63;
    for (int o = wv; o < 80; o += 4) {
        const float* w; float bb; float* dst;
        if (o < 50)      { w = w0 + (size_t)o * Hh;        bb = b0[o];      dst = out + o; }
        else if (o < 70) { w = w1 + (size_t)(o - 50) * Hh; bb = b1[o - 50]; dst = out + 150 + (o - 50); }
        else             { w = w2 + (size_t)(o - 70) * Hh; bb = b2[o - 70]; dst = out + 210 + (o - 70); }
        float s = 0.f;
        #pragma unroll
        for (int i = 0; i < 4; ++i) {
            const int k = (ln << 2) + (i << 8);
            const float4 ww = *(const float4*)&w[k];
            const float4 l4 = *(const float4*)&sl[k];
            s += ww.x * l4.x + ww.y * l4.y + ww.z * l4.z + ww.w * l4.w;
        }
        #pragma unroll
        for (int m = 1; m < 64; m <<= 1) s += __shfl_xor(s, m);
        if (ln == 0) *dst = s + bb;
    }
}

extern "C" void kernel_launch(void* const* d_in, const int* in_sizes, int n_in,
                              void* d_out, int out_size, void* d_ws, size_t ws_size,
                              hipStream_t stream)
{
    (void)in_sizes; (void)n_in; (void)out_size; (void)ws_size;
    const int*   char_seq  = (const int*)d_in[0];
    const int*   target    = (const int*)d_in[1];
    const float* enc_state = (const float*)d_in[2];
    const float* emb       = (const float*)d_in[3];
    const float* enc_wih0  = (const float*)d_in[4];
    const float* enc_whh0  = (const float*)d_in[5];
    const float* enc_bih0  = (const float*)d_in[6];
    const float* enc_bhh0  = (const float*)d_in[7];
    const float* enc_wih1  = (const float*)d_in[8];
    const float* enc_whh1  = (const float*)d_in[9];
    const float* enc_bih1  = (const float*)d_in[10];
    const float* enc_bhh1  = (const float*)d_in[11];
    const float* dec_wih0  = (const float*)d_in[12];
    const float* dec_whh0  = (const float*)d_in[13];
    const float* dec_bih0  = (const float*)d_in[14];
    const float* dec_bhh0  = (const float*)d_in[15];
    const float* dec_wih1  = (const float*)d_in[16];
    const float* dec_whh1  = (const float*)d_in[17];
    const float* dec_bih1  = (const float*)d_in[18];
    const float* dec_bhh1  = (const float*)d_in[19];
    const float* out_w     = (const float*)d_in[20];
    const float* out_b     = (const float*)d_in[21];
    const float* cls_w0    = (const float*)d_in[22];
    const float* cls_b0    = (const float*)d_in[23];
    const float* cls_w1    = (const float*)d_in[24];
    const float* cls_b1    = (const float*)d_in[25];
    const float* cls_w2    = (const float*)d_in[26];
    const float* cls_b2    = (const float*)d_in[27];
    const int*   sos       = (const int*)d_in[28];

    float* ws    = (float*)d_ws;
    float* x_enc = ws;                                   // 1024*512
    float* x_dec = x_enc + 1024 * 512;                   // 512*512
    float* gx    = x_dec + 512 * 512;                    // 1024*3072 (enc L0, then dec L0)
    float* hs_e0 = gx + 1024 * 3072;                     // 1025*1024 (row 0 unused)
    float* hs_e1 = hs_e0 + 1025 * 1024;                  // 1025*1024
    float* hs_d0 = hs_e1 + 1025 * 1024;                  // 513*1024
    float* hs_d1 = hs_d0 + 513 * 1024;                   // 513*1024

    float* out        = (float*)d_out;
    float* out_scores = out;                             // 512*1024
    float* out_states = out + 512 * 1024;                // 512*2048
    float* out_labels = out_states + 512 * 2048;         // 240

    // poison all hs rows: the data is its own ready-flag (re-done every launch -> replay-safe)
    hipMemsetAsync(hs_e0, 0xFF, (size_t)(1025 + 1025 + 513 + 513) * 1024 * sizeof(float), stream);

    gather_emb<<<1536, 128, 0, stream>>>(char_seq, target, sos, emb, x_enc, x_dec);

    // encoder: gx for layer0, then fused 2-layer dataflow recurrence
    gemm_nt<<<dim3(48, 16), 256, 0, stream>>>(x_enc, enc_wih0, enc_bih0, gx, 1024, 3072, 512);
    fused_gru2<<<256, 512, 0, stream>>>(gx, enc_whh0, enc_bhh0,
                                        enc_wih1, enc_bih1, enc_whh1, enc_bhh1,
                                        enc_state, enc_state + 1024,
                                        hs_e0, hs_e1, 1024);

    // decoder: gx for layer0 (reuses gx buffer), fused 2-layer dataflow recurrence
    gemm_nt<<<dim3(48, 8), 256, 0, stream>>>(x_dec, dec_wih0, dec_bih0, gx, 512, 3072, 512);
    fused_gru2<<<256, 512, 0, stream>>>(gx, dec_whh0, dec_bhh0,
                                        dec_wih1, dec_bih1, dec_whh1, dec_bhh1,
                                        hs_e0 + 1024 * 1024, hs_e1 + 1024 * 1024,
                                        hs_d0, hs_d1, 512);

    // char_scores -> d_out region 0
    gemm_nt<<<dim3(16, 8), 256, 0, stream>>>(hs_d1 + 1024, out_w, out_b, out_scores, 512, 1024, 1024);
    // char_states_out
    copy_states<<<1024, 256, 0, stream>>>(hs_d0, hs_d1, out_states);
    // label heads (+ padding zeros)
    labels_kernel<<<1, 256, 0, stream>>>(out_scores, cls_w0, cls_b0, cls_w1, cls_b1, cls_w2, cls_b2, out_labels);
}

// Round 5
// 5467.915 us; speedup vs baseline: 5.3203x; 5.3203x over previous
//
#include <hip/hip_runtime.h>
#include <hip/hip_bf16.h>
#include <cstdint>

#define Hh   1024
#define G3   3072
#define POISON_U 0xFFFFFFFFu

__device__ __forceinline__ float sigmoidf_(float x) { return 1.f / (1.f + __expf(-x)); }

__device__ __forceinline__ float ld_agent(const float* p) {
    return __hip_atomic_load(p, __ATOMIC_RELAXED, __HIP_MEMORY_SCOPE_AGENT);
}
__device__ __forceinline__ void st_agent(float* p, float v) {
    __hip_atomic_store(p, v, __ATOMIC_RELAXED, __HIP_MEMORY_SCOPE_AGENT);
}
__device__ __forceinline__ bool okf(float v) { return __float_as_uint(v) != POISON_U; }

// poll one float4 (4 concurrent agent loads) until all 4 elements are non-poison
__device__ __forceinline__ float4 poll4(const float* p) {
    float4 v;
    int guard = 0;
    for (;;) {
        v.x = ld_agent(p + 0); v.y = ld_agent(p + 1);
        v.z = ld_agent(p + 2); v.w = ld_agent(p + 3);
        if (okf(v.x) && okf(v.y) && okf(v.z) && okf(v.w)) break;
        if (++guard > (1 << 20)) break;   // paranoia: no infinite hang
        __builtin_amdgcn_s_sleep(1);
    }
    return v;
}

// ---------------- gather: x_enc = emb[char_seq], x_dec = emb[[sos]+target[:-1]] ----------------
__global__ __launch_bounds__(128) void gather_emb(const int* __restrict__ char_seq,
    const int* __restrict__ target, const int* __restrict__ sos,
    const float* __restrict__ emb, float* __restrict__ x_enc, float* __restrict__ x_dec)
{
    const int r = blockIdx.x;
    int id; float* dst;
    if (r < 1024) { id = char_seq[r]; dst = x_enc + (size_t)r * 512; }
    else {
        const int rd = r - 1024;
        id = (rd == 0) ? sos[0] : target[rd - 1];
        dst = x_dec + (size_t)rd * 512;
    }
    const float4* src = (const float4*)(emb + (size_t)id * 512);
    ((float4*)dst)[threadIdx.x] = src[threadIdx.x];
}

// ---------------- GEMM: C[M x N] = A[M x K] @ W[N x K]^T + bias[N]  (f32, 64x64 tile) ----------------
__global__ __launch_bounds__(256) void gemm_nt(const float* __restrict__ A,
    const float* __restrict__ W, const float* __restrict__ bias,
    float* __restrict__ C, int M, int N, int K)
{
    __shared__ float As[16][68];
    __shared__ float Ws[16][68];
    const int tid = threadIdx.x;
    const int tx = tid & 15, ty = tid >> 4;
    const int row0 = blockIdx.y * 64, col0 = blockIdx.x * 64;
    const int lr = tid >> 2;          // 0..63
    const int ls = (tid & 3) << 2;    // 0,4,8,12
    float acc[4][4] = {};
    for (int k0 = 0; k0 < K; k0 += 16) {
        const float4 a4 = *(const float4*)(A + (size_t)(row0 + lr) * K + k0 + ls);
        const float4 w4 = *(const float4*)(W + (size_t)(col0 + lr) * K + k0 + ls);
        As[ls + 0][lr] = a4.x; As[ls + 1][lr] = a4.y; As[ls + 2][lr] = a4.z; As[ls + 3][lr] = a4.w;
        Ws[ls + 0][lr] = w4.x; Ws[ls + 1][lr] = w4.y; Ws[ls + 2][lr] = w4.z; Ws[ls + 3][lr] = w4.w;
        __syncthreads();
        #pragma unroll
        for (int k = 0; k < 16; ++k) {
            const float4 a = *(const float4*)&As[k][ty << 2];
            const float4 w = *(const float4*)&Ws[k][tx << 2];
            const float av[4] = {a.x, a.y, a.z, a.w};
            const float wv[4] = {w.x, w.y, w.z, w.w};
            #pragma unroll
            for (int i = 0; i < 4; ++i)
                #pragma unroll
                for (int j = 0; j < 4; ++j)
                    acc[i][j] += av[i] * wv[j];
        }
        __syncthreads();
    }
    const int cc = col0 + (tx << 2);
    #pragma unroll
    for (int i = 0; i < 4; ++i) {
        float4 o;
        o.x = acc[i][0] + bias[cc + 0];
        o.y = acc[i][1] + bias[cc + 1];
        o.z = acc[i][2] + bias[cc + 2];
        o.w = acc[i][3] + bias[cc + 3];
        *(float4*)(C + (size_t)(row0 + (ty << 2) + i) * N + cc) = o;
    }
}

// ---------------- fused 2-layer GRU: register weights + LDS-shared poison-poll, 1 barrier/step ----------------
// Grid: 256 WGs x 512 threads. WGs 0..127 = layer0 (1 unit per wave), 128..255 = layer1.
// Fill phase: L0 -> threads 0..255 poll one float4 of hs0[t] each into LDS buffer (t&1).
//             L1 -> threads 0..255 poll hs0[t+1], threads 256..511 poll hs1[t].
// Double-buffered LDS + single __syncthreads per step (fill(t+1) writes the other buffer,
// so laggards still reading buffer t&1 are safe; skew < 1 iteration).
// hs rows poisoned 0xFFFFFFFF at launch; writers publish via relaxed agent 4B stores.
__global__ __launch_bounds__(512) void fused_gru2(
    const float* __restrict__ gx0,
    const float* __restrict__ whh0, const float* __restrict__ bhh0,
    const float* __restrict__ wih1, const float* __restrict__ bih1,
    const float* __restrict__ whh1, const float* __restrict__ bhh1,
    const float* __restrict__ h0i, const float* __restrict__ h1i,
    float* __restrict__ hs0, float* __restrict__ hs1, int S)
{
    __shared__ float shA[2][Hh];     // L0: h0_prev | L1: x (= hs0[t+1])
    __shared__ float shB[2][Hh];     // L1 only: h1_prev
    const int tid = threadIdx.x;
    const int wg  = blockIdx.x;
    const bool isL1 = (wg >= 128);
    const int ln = tid & 63;
    const int wv = tid >> 6;                             // 0..7
    const int uu = ((isL1 ? wg - 128 : wg) << 3) + wv;   // hidden unit 0..1023
    const int base = ln << 2;

    // --- loop-invariant weights into VGPRs ---
    float4 wa[3][4], wb[3][4];
    const float* WA = isL1 ? wih1 : whh0;
    #pragma unroll
    for (int g = 0; g < 3; ++g)
        #pragma unroll
        for (int j = 0; j < 4; ++j)
            wa[g][j] = *(const float4*)(WA + (size_t)(g * Hh + uu) * Hh + base + (j << 8));
    if (isL1) {
        #pragma unroll
        for (int g = 0; g < 3; ++g)
            #pragma unroll
            for (int j = 0; j < 4; ++j)
                wb[g][j] = *(const float4*)(whh1 + (size_t)(g * Hh + uu) * Hh + base + (j << 8));
    } else {
        #pragma unroll
        for (int g = 0; g < 3; ++g)
            #pragma unroll
            for (int j = 0; j < 4; ++j)
                wb[g][j] = make_float4(0.f, 0.f, 0.f, 0.f);
    }
    const float* BA = isL1 ? bih1 : bhh0;
    const float ba_r = BA[uu], ba_z = BA[Hh + uu], ba_n = BA[2 * Hh + uu];
    const float bb_r = isL1 ? bhh1[uu] : 0.f;
    const float bb_z = isL1 ? bhh1[Hh + uu] : 0.f;
    const float bb_n = isL1 ? bhh1[2 * Hh + uu] : 0.f;

    for (int t = 0; t < S; ++t) {
        const int b = t & 1;
        // gx row loads (L0 only) issued early, overlap the fill
        float xr = 0.f, xz = 0.f, xn = 0.f;
        if (!isL1) {
            const float* gxt = gx0 + (size_t)t * G3 + uu;
            xr = gxt[0]; xz = gxt[Hh]; xn = gxt[2 * Hh];
        }

        // --- fill phase: one float4 per participating thread ---
        if (!isL1) {
            if (tid < 256) {
                const int off = tid << 2;
                float4 v;
                if (t == 0) v = *(const float4*)(h0i + off);
                else        v = poll4(hs0 + (size_t)t * Hh + off);
                *(float4*)&shA[b][off] = v;
            }
        } else {
            if (tid < 256) {
                const int off = tid << 2;
                const float4 v = poll4(hs0 + (size_t)(t + 1) * Hh + off);   // always in-flight
                *(float4*)&shA[b][off] = v;
            } else {
                const int off = (tid - 256) << 2;
                float4 v;
                if (t == 0) v = *(const float4*)(h1i + off);
                else        v = poll4(hs1 + (size_t)t * Hh + off);
                *(float4*)&shB[b][off] = v;
            }
        }
        __syncthreads();

        // --- gates ---
        const float4* sA = (const float4*)shA[b];
        const float4* sB = (const float4*)shB[b];
        float ar = 0.f, az = 0.f, an = 0.f, hr = 0.f, hz = 0.f, hn = 0.f;
        #pragma unroll
        for (int j = 0; j < 4; ++j) {
            const float4 x4 = sA[ln + 64 * j];
            ar += x4.x * wa[0][j].x + x4.y * wa[0][j].y + x4.z * wa[0][j].z + x4.w * wa[0][j].w;
            az += x4.x * wa[1][j].x + x4.y * wa[1][j].y + x4.z * wa[1][j].z + x4.w * wa[1][j].w;
            an += x4.x * wa[2][j].x + x4.y * wa[2][j].y + x4.z * wa[2][j].z + x4.w * wa[2][j].w;
        }
        if (isL1) {
            #pragma unroll
            for (int j = 0; j < 4; ++j) {
                const float4 h4 = sB[ln + 64 * j];
                hr += h4.x * wb[0][j].x + h4.y * wb[0][j].y + h4.z * wb[0][j].z + h4.w * wb[0][j].w;
                hz += h4.x * wb[1][j].x + h4.y * wb[1][j].y + h4.z * wb[1][j].z + h4.w * wb[1][j].w;
                hn += h4.x * wb[2][j].x + h4.y * wb[2][j].y + h4.z * wb[2][j].z + h4.w * wb[2][j].w;
            }
        }
        #pragma unroll
        for (int m = 1; m < 64; m <<= 1) {
            ar += __shfl_xor(ar, m); az += __shfl_xor(az, m); an += __shfl_xor(an, m);
            if (isL1) { hr += __shfl_xor(hr, m); hz += __shfl_xor(hz, m); hn += __shfl_xor(hn, m); }
        }
        if (ln == 0) {
            float rr, zz, nn, hprev;
            if (!isL1) {
                rr = sigmoidf_(xr + ar + ba_r);
                zz = sigmoidf_(xz + az + ba_z);
                nn = tanhf(xn + rr * (an + ba_n));
                hprev = shA[b][uu];
            } else {
                rr = sigmoidf_((ar + ba_r) + (hr + bb_r));
                zz = sigmoidf_((az + ba_z) + (hz + bb_z));
                nn = tanhf((an + ba_n) + rr * (hn + bb_n));
                hprev = shB[b][uu];
            }
            const float hnew = (1.f - zz) * nn + zz * hprev;
            st_agent((isL1 ? hs1 : hs0) + (size_t)(t + 1) * Hh + uu, hnew);
        }
        // no trailing barrier: next fill writes buffer (t+1)&1, distinct from b
    }
}

// ---------------- char_states_out: out[t][0:1024]=hs_d0[t+1], out[t][1024:2048]=hs_d1[t+1] ----------------
__global__ __launch_bounds__(256) void copy_states(const float* __restrict__ hs0,
    const float* __restrict__ hs1, float* __restrict__ out)
{
    const int f = blockIdx.x * 256 + threadIdx.x;  // float4 index, total 262144
    const int t = f >> 9;
    const int c = f & 511;
    const float* src = (c < 256) ? (hs0 + (((size_t)t + 1) << 10) + (c << 2))
                                 : (hs1 + (((size_t)t + 1) << 10) + ((c - 256) << 2));
    *(float4*)(out + ((size_t)f << 2)) = *(const float4*)src;
}

// ---------------- label heads on char_scores[last] + zero padding ----------------
__global__ __launch_bounds__(256) void labels_kernel(const float* __restrict__ scores,
    const float* __restrict__ w0, const float* __restrict__ b0,
    const float* __restrict__ w1, const float* __restrict__ b1,
    const float* __restrict__ w2, const float* __restrict__ b2,
    float* __restrict__ out)
{
    __shared__ float sl[Hh];
    const int tid = threadIdx.x;
    for (int i = tid; i < Hh; i += 256) sl[i] = scores[(size_t)511 * Hh + i];
    for (int i = tid; i < 240; i += 256) out[i] = 0.f;
    __syncthreads();
    const int wv = tid >> 6, ln = tid & 63;
    for (int o = wv; o < 80; o += 4) {
        const float* w; float bb; float* dst;
        if (o < 50)      { w = w0 + (size_t)o * Hh;        bb = b0[o];      dst = out + o; }
        else if (o < 70) { w = w1 + (size_t)(o - 50) * Hh; bb = b1[o - 50]; dst = out + 150 + (o - 50); }
        else             { w = w2 + (size_t)(o - 70) * Hh; bb = b2[o - 70]; dst = out + 210 + (o - 70); }
        float s = 0.f;
        #pragma unroll
        for (int i = 0; i < 4; ++i) {
            const int k = (ln << 2) + (i << 8);
            const float4 ww = *(const float4*)&w[k];
            const float4 l4 = *(const float4*)&sl[k];
            s += ww.x * l4.x + ww.y * l4.y + ww.z * l4.z + ww.w * l4.w;
        }
        #pragma unroll
        for (int m = 1; m < 64; m <<= 1) s += __shfl_xor(s, m);
        if (ln == 0) *dst = s + bb;
    }
}

extern "C" void kernel_launch(void* const* d_in, const int* in_sizes, int n_in,
                              void* d_out, int out_size, void* d_ws, size_t ws_size,
                              hipStream_t stream)
{
    (void)in_sizes; (void)n_in; (void)out_size; (void)ws_size;
    const int*   char_seq  = (const int*)d_in[0];
    const int*   target    = (const int*)d_in[1];
    const float* enc_state = (const float*)d_in[2];
    const float* emb       = (const float*)d_in[3];
    const float* enc_wih0  = (const float*)d_in[4];
    const float* enc_whh0  = (const float*)d_in[5];
    const float* enc_bih0  = (const float*)d_in[6];
    const float* enc_bhh0  = (const float*)d_in[7];
    const float* enc_wih1  = (const float*)d_in[8];
    const float* enc_whh1  = (const float*)d_in[9];
    const float* enc_bih1  = (const float*)d_in[10];
    const float* enc_bhh1  = (const float*)d_in[11];
    const float* dec_wih0  = (const float*)d_in[12];
    const float* dec_whh0  = (const float*)d_in[13];
    const float* dec_bih0  = (const float*)d_in[14];
    const float* dec_bhh0  = (const float*)d_in[15];
    const float* dec_wih1  = (const float*)d_in[16];
    const float* dec_whh1  = (const float*)d_in[17];
    const float* dec_bih1  = (const float*)d_in[18];
    const float* dec_bhh1  = (const float*)d_in[19];
    const float* out_w     = (const float*)d_in[20];
    const float* out_b     = (const float*)d_in[21];
    const float* cls_w0    = (const float*)d_in[22];
    const float* cls_b0    = (const float*)d_in[23];
    const float* cls_w1    = (const float*)d_in[24];
    const float* cls_b1    = (const float*)d_in[25];
    const float* cls_w2    = (const float*)d_in[26];
    const float* cls_b2    = (const float*)d_in[27];
    const int*   sos       = (const int*)d_in[28];

    float* ws    = (float*)d_ws;
    float* x_enc = ws;                                   // 1024*512
    float* x_dec = x_enc + 1024 * 512;                   // 512*512
    float* gx    = x_dec + 512 * 512;                    // 1024*3072 (enc L0, then dec L0)
    float* hs_e0 = gx + 1024 * 3072;                     // 1025*1024 (row 0 unused)
    float* hs_e1 = hs_e0 + 1025 * 1024;                  // 1025*1024
    float* hs_d0 = hs_e1 + 1025 * 1024;                  // 513*1024
    float* hs_d1 = hs_d0 + 513 * 1024;                   // 513*1024

    float* out        = (float*)d_out;
    float* out_scores = out;                             // 512*1024
    float* out_states = out + 512 * 1024;                // 512*2048
    float* out_labels = out_states + 512 * 2048;         // 240

    // poison all hs rows: the data is its own ready-flag (re-done every launch -> replay-safe)
    hipMemsetAsync(hs_e0, 0xFF, (size_t)(1025 + 1025 + 513 + 513) * 1024 * sizeof(float), stream);

    gather_emb<<<1536, 128, 0, stream>>>(char_seq, target, sos, emb, x_enc, x_dec);

    // encoder: gx for layer0, then fused 2-layer dataflow recurrence
    gemm_nt<<<dim3(48, 16), 256, 0, stream>>>(x_enc, enc_wih0, enc_bih0, gx, 1024, 3072, 512);
    fused_gru2<<<256, 512, 0, stream>>>(gx, enc_whh0, enc_bhh0,
                                        enc_wih1, enc_bih1, enc_whh1, enc_bhh1,
                                        enc_state, enc_state + 1024,
                                        hs_e0, hs_e1, 1024);

    // decoder: gx for layer0 (reuses gx buffer), fused 2-layer dataflow recurrence
    gemm_nt<<<dim3(48, 8), 256, 0, stream>>>(x_dec, dec_wih0, dec_bih0, gx, 512, 3072, 512);
    fused_gru2<<<256, 512, 0, stream>>>(gx, dec_whh0, dec_bhh0,
                                        dec_wih1, dec_bih1, dec_whh1, dec_bhh1,
                                        hs_e0 + 1024 * 1024, hs_e1 + 1024 * 1024,
                                        hs_d0, hs_d1, 512);

    // char_scores -> d_out region 0
    gemm_nt<<<dim3(16, 8), 256, 0, stream>>>(hs_d1 + 1024, out_w, out_b, out_scores, 512, 1024, 1024);
    // char_states_out
    copy_states<<<1024, 256, 0, stream>>>(hs_d0, hs_d1, out_states);
    // label heads (+ padding zeros)
    labels_kernel<<<1, 256, 0, stream>>>(out_scores, cls_w0, cls_b0, cls_w1, cls_b1, cls_w2, cls_b2, out_labels);
}